// Round 5
// baseline (299.023 us; speedup 1.0000x reference)
//
#include <hip/hip_runtime.h>
#include <hip/hip_fp16.h>
#include <hip/hip_cooperative_groups.h>

namespace cg = cooperative_groups;

#define D_FEAT 128
#define THRESH 0.01f
#define EPS_F  1e-8f

typedef _Float16 half2_t __attribute__((ext_vector_type(2)));

// ---------------------------------------------------------------------------
// Exact helpers: bit-exact replication of numpy's fp32 pipeline
// (8-accumulator pairwise sum). Proven absmax=0 in prior rounds.
// ---------------------------------------------------------------------------

__device__ float edge_out_scalar(const float* __restrict__ feat,
                                 float w, int s, int d) {
#pragma clang fp contract(off)
    const float* fs = feat + (size_t)s * D_FEAT;
    const float* fd = feat + (size_t)d * D_FEAT;
    float r[8], rs[8], rd[8];
#pragma unroll
    for (int j = 0; j < 8; ++j) {
        float a = fs[j], b = fd[j];
        r[j]  = a * b;
        rs[j] = a * a;
        rd[j] = b * b;
    }
    for (int k = 1; k < 16; ++k) {
#pragma unroll
        for (int j = 0; j < 8; ++j) {
            float a = fs[8 * k + j], b = fd[8 * k + j];
            r[j]  = r[j]  + a * b;
            rs[j] = rs[j] + a * a;
            rd[j] = rd[j] + b * b;
        }
    }
    float inner = ((r[0]  + r[1])  + (r[2]  + r[3]))  + ((r[4]  + r[5])  + (r[6]  + r[7]));
    float ss    = ((rs[0] + rs[1]) + (rs[2] + rs[3])) + ((rs[4] + rs[5]) + (rs[6] + rs[7]));
    float dd    = ((rd[0] + rd[1]) + (rd[2] + rd[3])) + ((rd[4] + rd[5]) + (rd[6] + rd[7]));
    float ns = __fsqrt_rn(ss);
    float nd = __fsqrt_rn(dd);
    float denom = ns * nd + EPS_F;
    float sim = inner / denom;
    float keep = (sim >= THRESH) ? 1.0f : 0.0f;
    float diag = (s == d) ? 2.0f : 1.0f;
    return (w * keep) * diag;
}

__device__ __forceinline__ float exact_sim_pairlanes(const float* __restrict__ feat,
                                                     int src, int dst, int h) {
#pragma clang fp contract(off)
    const float4* fs = (const float4*)(feat + (size_t)src * D_FEAT);
    const float4* fd = (const float4*)(feat + (size_t)dst * D_FEAT);
    float r[4], rs[4], rd[4];
    {
        float4 a = fs[h];
        float4 b = fd[h];
        r[0]  = a.x * b.x; r[1]  = a.y * b.y; r[2]  = a.z * b.z; r[3]  = a.w * b.w;
        rs[0] = a.x * a.x; rs[1] = a.y * a.y; rs[2] = a.z * a.z; rs[3] = a.w * a.w;
        rd[0] = b.x * b.x; rd[1] = b.y * b.y; rd[2] = b.z * b.z; rd[3] = b.w * b.w;
    }
#pragma unroll
    for (int k = 1; k < 16; ++k) {
        float4 a = fs[2 * k + h];
        float4 b = fd[2 * k + h];
        r[0]  = r[0]  + a.x * b.x;  r[1]  = r[1]  + a.y * b.y;
        r[2]  = r[2]  + a.z * b.z;  r[3]  = r[3]  + a.w * b.w;
        rs[0] = rs[0] + a.x * a.x;  rs[1] = rs[1] + a.y * a.y;
        rs[2] = rs[2] + a.z * a.z;  rs[3] = rs[3] + a.w * a.w;
        rd[0] = rd[0] + b.x * b.x;  rd[1] = rd[1] + b.y * b.y;
        rd[2] = rd[2] + b.z * b.z;  rd[3] = rd[3] + b.w * b.w;
    }
    float A  = (r[0]  + r[1])  + (r[2]  + r[3]);
    float As = (rs[0] + rs[1]) + (rs[2] + rs[3]);
    float Ad = (rd[0] + rd[1]) + (rd[2] + rd[3]);

    float inner = A  + __shfl_xor(A, 1, 64);
    float ssE   = As + __shfl_xor(As, 1, 64);
    float ddE   = Ad + __shfl_xor(Ad, 1, 64);

    float ns    = __fsqrt_rn(ssE);
    float nd    = __fsqrt_rn(ddE);
    float den   = ns * nd + EPS_F;
    return inner / den;
}

__device__ __forceinline__ float exact_inner_pairlanes(const float* __restrict__ feat,
                                                       int src, int dst, int h) {
#pragma clang fp contract(off)
    const float4* fs = (const float4*)(feat + (size_t)src * D_FEAT);
    const float4* fd = (const float4*)(feat + (size_t)dst * D_FEAT);
    float r[4];
    {
        float4 a = fs[h];
        float4 b = fd[h];
        r[0] = a.x * b.x; r[1] = a.y * b.y; r[2] = a.z * b.z; r[3] = a.w * b.w;
    }
#pragma unroll
    for (int k = 1; k < 16; ++k) {
        float4 a = fs[2 * k + h];
        float4 b = fd[2 * k + h];
        r[0] = r[0] + a.x * b.x;  r[1] = r[1] + a.y * b.y;
        r[2] = r[2] + a.z * b.z;  r[3] = r[3] + a.w * b.w;
    }
    float A = (r[0] + r[1]) + (r[2] + r[3]);
    return A + __shfl_xor(A, 1, 64);
}

// ---------------------------------------------------------------------------
// fdot2 helper
// ---------------------------------------------------------------------------
__device__ __forceinline__ float dot8_f16(uint4 ua, uint4 ub, float acc) {
    acc = __builtin_amdgcn_fdot2(__builtin_bit_cast(half2_t, ua.x),
                                 __builtin_bit_cast(half2_t, ub.x), acc, false);
    acc = __builtin_amdgcn_fdot2(__builtin_bit_cast(half2_t, ua.y),
                                 __builtin_bit_cast(half2_t, ub.y), acc, false);
    acc = __builtin_amdgcn_fdot2(__builtin_bit_cast(half2_t, ua.z),
                                 __builtin_bit_cast(half2_t, ub.z), acc, false);
    acc = __builtin_amdgcn_fdot2(__builtin_bit_cast(half2_t, ua.w),
                                 __builtin_bit_cast(half2_t, ub.w), acc, false);
    return acc;
}

// ---------------------------------------------------------------------------
// Fallback kernel (ws too small / odd feature count): round-1 proven path.
// ---------------------------------------------------------------------------
__global__ __launch_bounds__(256) void jaccard_edge_kernel(
    const int* __restrict__ ei, const float* __restrict__ w,
    const float* __restrict__ feat, float* __restrict__ out,
    int P, int E)
{
    int t    = blockIdx.x * blockDim.x + threadIdx.x;
    int pair = t >> 1;
    int half = t & 1;
    if (pair >= P) return;

    int src = ei[pair];
    int dst = ei[E + pair];

    float sim  = exact_sim_pairlanes(feat, src, dst, half);
    float keep = (sim >= THRESH) ? 1.0f : 0.0f;

    if (half == 0) {
        float diag = (src == dst) ? 2.0f : 1.0f;
        out[pair] = (w[pair] * keep) * diag;
        int m = P + pair;
        if (m < E) {
            int s2 = ei[m];
            int d2 = ei[E + m];
            if (s2 == dst && d2 == src) out[m] = (w[m] * keep) * diag;
            else                        out[m] = edge_out_scalar(feat, w[m], s2, d2);
        }
    }
}

// ---------------------------------------------------------------------------
// Phase A body (proven exact, round-4 v4): one quad per node, registers only.
// Lane q holds elements {8k+2q, 8k+2q+1} = float2 index 4k+q; sequential k ==
// numpy order; shfl_xor(1),(2) == numpy pairwise tree. Bad rows NaN-poisoned.
// ---------------------------------------------------------------------------
__device__ __forceinline__ void phaseA_node(const float* __restrict__ feat,
                                            __half* __restrict__ hfeat,
                                            float* __restrict__ nrm,
                                            int n, int q) {
#pragma clang fp contract(off)
    const float2* row = (const float2*)(feat + (size_t)n * D_FEAT);
    float2 v[16];
#pragma unroll
    for (int k = 0; k < 16; ++k) v[k] = row[4 * k + q];

    float r0 = v[0].x * v[0].x;
    float r1 = v[0].y * v[0].y;
#pragma unroll
    for (int k = 1; k < 16; ++k) {
        r0 = r0 + v[k].x * v[k].x;
        r1 = r1 + v[k].y * v[k].y;
    }
    float s  = r0 + r1;                     // r[2q] + r[2q+1]
    float ss = s + __shfl_xor(s, 1, 64);    // (s0+s1) | (s2+s3)
    ss       = ss + __shfl_xor(ss, 2, 64);  // full numpy tree (quad-local)
    float na = __fsqrt_rn(ss);

    bool ok  = isfinite(na) && (na >= 0.03f);
    float r  = ok ? (1.0f / na) : __builtin_nanf("");

    if (q == 0) nrm[n] = na;                // exact numpy node_norm

    __half* orow = hfeat + (size_t)n * D_FEAT;
#pragma unroll
    for (int k = 0; k < 16; ++k) {
        __half2 h = __floats2half2_rn(v[k].x * r, v[k].y * r);
        *(__half2*)(orow + 8 * k + 2 * q) = h;
    }
}

// ---------------------------------------------------------------------------
// Phase B body (proven 56 µs): 4 lanes/pair, fdot2 screen vs CONSTANT bound
// 1.2e-3; |dot|>=2 or NaN -> exact; borderline -> exact fp32 numpy sim.
// ---------------------------------------------------------------------------
__device__ __forceinline__ void phaseB_pair(
    const int* __restrict__ ei, const float* __restrict__ w,
    const float* __restrict__ feat, const __half* __restrict__ hfeat,
    const float* __restrict__ nrm, float* __restrict__ out,
    int pair, int q, int P, int E)
{
#pragma clang fp contract(off)
    int src = __builtin_nontemporal_load(ei + pair);
    int dst = __builtin_nontemporal_load(ei + E + pair);

    float wp  = __builtin_nontemporal_load(w + pair);
    int   m   = P + pair;
    bool  hasm = (m < E);
    int s2 = 0, d2 = 0;
    float wm = 0.f;
    if (hasm) {
        s2 = __builtin_nontemporal_load(ei + m);
        d2 = __builtin_nontemporal_load(ei + E + m);
        wm = __builtin_nontemporal_load(w + m);
    }

    const uint4* ha = (const uint4*)(hfeat + (size_t)src * D_FEAT);
    const uint4* hb = (const uint4*)(hfeat + (size_t)dst * D_FEAT);

    uint4 A[4], B[4];
#pragma unroll
    for (int k = 0; k < 4; ++k) {
        A[k] = ha[4 * k + q];
        B[k] = hb[4 * k + q];
    }

    float d = 0.f;
#pragma unroll
    for (int k = 0; k < 4; ++k) d = dot8_f16(A[k], B[k], d);

    // quad butterfly: bit-identical on all 4 lanes (IEEE a+b==b+a)
    d += __shfl_xor(d, 1, 64);
    float dot = d + __shfl_xor(d, 2, 64);

    float diff = dot - THRESH;
    const float bnd = 1.2e-3f;

    float keep;
    if (fabsf(diff) > bnd && fabsf(dot) < 2.0f) {   // quad-uniform decision
        keep = (diff >= 0.f) ? 1.0f : 0.0f;
    } else {
        float se = 0.f;
        if (q < 2) {
            float inner = exact_inner_pairlanes(feat, src, dst, q);
            float den   = nrm[src] * nrm[dst] + EPS_F;   // mul then add
            se = inner / den;
        }
        keep = (se >= THRESH) ? 1.0f : 0.0f;   // valid on lane q==0 (writer)
    }

    if (q == 0) {
        float diag = (src == dst) ? 2.0f : 1.0f;
        __builtin_nontemporal_store((wp * keep) * diag, out + pair);
        if (hasm) {
            if (s2 == dst && d2 == src) {
                __builtin_nontemporal_store((wm * keep) * diag, out + m);
            } else {
                out[m] = edge_out_scalar(feat, wm, s2, d2);
            }
        }
    }
}

// ---------------------------------------------------------------------------
// Standalone pass A / pass B kernels (non-cooperative fallback path).
// ---------------------------------------------------------------------------
__global__ __launch_bounds__(256) void norm_convert_kernel(
    const float* __restrict__ feat, __half* __restrict__ hfeat,
    float* __restrict__ nrm, int nNodes)
{
    int tid  = blockIdx.x * blockDim.x + threadIdx.x;
    int lane = tid & 63;
    int n    = (tid >> 6) * 16 + (lane >> 2);
    int q    = lane & 3;
    if (n >= nNodes) return;    // quad-uniform exit
    phaseA_node(feat, hfeat, nrm, n, q);
}

__global__ __launch_bounds__(256) void jaccard_edge_f16u_kernel(
    const int* __restrict__ ei, const float* __restrict__ w,
    const float* __restrict__ feat, const __half* __restrict__ hfeat,
    const float* __restrict__ nrm, float* __restrict__ out, int P, int E)
{
    int t    = blockIdx.x * blockDim.x + threadIdx.x;
    int pair = t >> 2;
    int q    = t & 3;
    if (pair >= P) return;
    phaseB_pair(ei, w, feat, hfeat, nrm, out, pair, q, P, E);
}

// ---------------------------------------------------------------------------
// Fused cooperative kernel: phase A (grid-stride) -> threadfence + grid.sync
// -> phase B (grid-stride). Stride is a multiple of 64, so HW lane index and
// quad-partner relationships are invariant across iterations -> shuffles and
// lane->element mappings identical to the standalone kernels -> bit-exact.
// ---------------------------------------------------------------------------
__global__ __launch_bounds__(256) void jaccard_fused_kernel(
    const int* __restrict__ ei, const float* __restrict__ w,
    const float* __restrict__ feat, __half* __restrict__ hfeat,
    float* __restrict__ nrm, float* __restrict__ out,
    int P, int E, int nNodes)
{
    cg::grid_group grid = cg::this_grid();
    long tid0   = (long)blockIdx.x * 256 + threadIdx.x;
    long stride = (long)gridDim.x * 256;

    // ---- Phase A: wave-padded quad-per-node ----
    long nQuadT = ((long)(nNodes + 15) / 16) * 64;
    for (long t = tid0; t < nQuadT; t += stride) {
        int lane = (int)(t & 63);
        int n    = (int)((t >> 6) * 16 + (lane >> 2));
        int q    = lane & 3;
        if (n < nNodes)                     // quad-uniform predicate
            phaseA_node(feat, hfeat, nrm, n, q);
    }

    __threadfence();     // device-scope release (cross-XCD visibility)
    grid.sync();

    // ---- Phase B: 4 lanes per pair ----
    long nPairT = (long)4 * P;
    for (long t = tid0; t < nPairT; t += stride) {
        int pair = (int)(t >> 2);
        int q    = (int)(t & 3);
        phaseB_pair(ei, w, feat, hfeat, nrm, out, pair, q, P, E);
    }
}

extern "C" void kernel_launch(void* const* d_in, const int* in_sizes, int n_in,
                              void* d_out, int out_size, void* d_ws, size_t ws_size,
                              hipStream_t stream) {
    const int*   ei   = (const int*)d_in[0];     // [2, E] flattened (int32)
    const float* w    = (const float*)d_in[1];   // [E]
    const float* feat = (const float*)d_in[2];   // [N, 128]
    float*       out  = (float*)d_out;           // [E]

    int E = in_sizes[1];
    int P = E - E / 2;                 // ceil(E/2)
    long nfeat = in_sizes[2];
    long nNodes = nfeat / D_FEAT;
    size_t need = (size_t)nfeat * sizeof(__half) + (size_t)nNodes * sizeof(float);

    if (P <= 0) return;

    if (ws_size < need || (nfeat % D_FEAT) != 0) {
        int threads = 2 * P;
        int grid = (threads + 255) / 256;
        jaccard_edge_kernel<<<grid, 256, 0, stream>>>(ei, w, feat, out, P, E);
        return;
    }

    __half* hfeat = (__half*)d_ws;
    float*  nrm   = (float*)((char*)d_ws + (size_t)nfeat * sizeof(__half));
    int nN = (int)nNodes;

    // One-time device/occupancy queries (not stream ops; graph-capture safe).
    static int coop = -1;
    static int numCU = 0;
    static int maxBpc = 0;
    if (coop < 0) {
        int dev = 0;
        hipGetDevice(&dev);
        int c = 0;
        hipDeviceGetAttribute(&c, hipDeviceAttributeCooperativeLaunch, dev);
        hipDeviceGetAttribute(&numCU, hipDeviceAttributeMultiprocessorCount, dev);
        hipOccupancyMaxActiveBlocksPerMultiprocessor(&maxBpc,
            (const void*)jaccard_fused_kernel, 256, 0);
        coop = (c && numCU > 0 && maxBpc > 0) ? 1 : 0;
    }

    if (coop) {
        long nQuadT = ((nNodes + 15) / 16) * 64;
        long needA  = (nQuadT + 255) / 256;
        long needB  = ((long)4 * P + 255) / 256;
        long needBl = needA > needB ? needA : needB;
        long cap    = (long)maxBpc * numCU;
        long gridF  = needBl < cap ? needBl : cap;
        if (gridF < 1) gridF = 1;

        void* args[] = {(void*)&ei, (void*)&w, (void*)&feat, (void*)&hfeat,
                        (void*)&nrm, (void*)&out, (void*)&P, (void*)&E, (void*)&nN};
        hipError_t err = hipLaunchCooperativeKernel(
            (const void*)jaccard_fused_kernel, dim3((unsigned)gridF), dim3(256),
            args, 0, stream);
        if (err == hipSuccess) return;
        // fall through to two-kernel path on any launch failure
    }

    long nWaves = (nNodes + 15) / 16;
    long tA = nWaves * 64;
    int gridA = (int)((tA + 255) / 256);
    norm_convert_kernel<<<gridA, 256, 0, stream>>>(feat, hfeat, nrm, nN);

    int tB = 4 * P;
    jaccard_edge_f16u_kernel<<<(tB + 255) / 256, 256, 0, stream>>>(
        ei, w, feat, hfeat, nrm, out, P, E);
}

// Round 9
// 157.239 us; speedup vs baseline: 1.9017x; 1.9017x over previous
//
#include <hip/hip_runtime.h>
#include <hip/hip_fp16.h>

#define D_FEAT 128
#define THRESH 0.01f
#define EPS_F  1e-8f

typedef _Float16 half2_t __attribute__((ext_vector_type(2)));

// ---------------------------------------------------------------------------
// Exact helpers: bit-exact replication of numpy's fp32 pipeline
// (8-accumulator pairwise sum). Proven absmax=0 in prior rounds.
// ---------------------------------------------------------------------------

__device__ float edge_out_scalar(const float* __restrict__ feat,
                                 float w, int s, int d) {
#pragma clang fp contract(off)
    const float* fs = feat + (size_t)s * D_FEAT;
    const float* fd = feat + (size_t)d * D_FEAT;
    float r[8], rs[8], rd[8];
#pragma unroll
    for (int j = 0; j < 8; ++j) {
        float a = fs[j], b = fd[j];
        r[j]  = a * b;
        rs[j] = a * a;
        rd[j] = b * b;
    }
    for (int k = 1; k < 16; ++k) {
#pragma unroll
        for (int j = 0; j < 8; ++j) {
            float a = fs[8 * k + j], b = fd[8 * k + j];
            r[j]  = r[j]  + a * b;
            rs[j] = rs[j] + a * a;
            rd[j] = rd[j] + b * b;
        }
    }
    float inner = ((r[0]  + r[1])  + (r[2]  + r[3]))  + ((r[4]  + r[5])  + (r[6]  + r[7]));
    float ss    = ((rs[0] + rs[1]) + (rs[2] + rs[3])) + ((rs[4] + rs[5]) + (rs[6] + rs[7]));
    float dd    = ((rd[0] + rd[1]) + (rd[2] + rd[3])) + ((rd[4] + rd[5]) + (rd[6] + rd[7]));
    float ns = __fsqrt_rn(ss);
    float nd = __fsqrt_rn(dd);
    float denom = ns * nd + EPS_F;
    float sim = inner / denom;
    float keep = (sim >= THRESH) ? 1.0f : 0.0f;
    float diag = (s == d) ? 2.0f : 1.0f;
    return (w * keep) * diag;
}

__device__ __forceinline__ float exact_sim_pairlanes(const float* __restrict__ feat,
                                                     int src, int dst, int h) {
#pragma clang fp contract(off)
    const float4* fs = (const float4*)(feat + (size_t)src * D_FEAT);
    const float4* fd = (const float4*)(feat + (size_t)dst * D_FEAT);
    float r[4], rs[4], rd[4];
    {
        float4 a = fs[h];
        float4 b = fd[h];
        r[0]  = a.x * b.x; r[1]  = a.y * b.y; r[2]  = a.z * b.z; r[3]  = a.w * b.w;
        rs[0] = a.x * a.x; rs[1] = a.y * a.y; rs[2] = a.z * a.z; rs[3] = a.w * a.w;
        rd[0] = b.x * b.x; rd[1] = b.y * b.y; rd[2] = b.z * b.z; rd[3] = b.w * b.w;
    }
#pragma unroll
    for (int k = 1; k < 16; ++k) {
        float4 a = fs[2 * k + h];
        float4 b = fd[2 * k + h];
        r[0]  = r[0]  + a.x * b.x;  r[1]  = r[1]  + a.y * b.y;
        r[2]  = r[2]  + a.z * b.z;  r[3]  = r[3]  + a.w * b.w;
        rs[0] = rs[0] + a.x * a.x;  rs[1] = rs[1] + a.y * a.y;
        rs[2] = rs[2] + a.z * a.z;  rs[3] = rs[3] + a.w * a.w;
        rd[0] = rd[0] + b.x * b.x;  rd[1] = rd[1] + b.y * b.y;
        rd[2] = rd[2] + b.z * b.z;  rd[3] = rd[3] + b.w * b.w;
    }
    float A  = (r[0]  + r[1])  + (r[2]  + r[3]);
    float As = (rs[0] + rs[1]) + (rs[2] + rs[3]);
    float Ad = (rd[0] + rd[1]) + (rd[2] + rd[3]);

    float inner = A  + __shfl_xor(A, 1, 64);
    float ssE   = As + __shfl_xor(As, 1, 64);
    float ddE   = Ad + __shfl_xor(Ad, 1, 64);

    float ns    = __fsqrt_rn(ssE);
    float nd    = __fsqrt_rn(ddE);
    float den   = ns * nd + EPS_F;
    return inner / den;
}

__device__ __forceinline__ float exact_inner_pairlanes(const float* __restrict__ feat,
                                                       int src, int dst, int h) {
#pragma clang fp contract(off)
    const float4* fs = (const float4*)(feat + (size_t)src * D_FEAT);
    const float4* fd = (const float4*)(feat + (size_t)dst * D_FEAT);
    float r[4];
    {
        float4 a = fs[h];
        float4 b = fd[h];
        r[0] = a.x * b.x; r[1] = a.y * b.y; r[2] = a.z * b.z; r[3] = a.w * b.w;
    }
#pragma unroll
    for (int k = 1; k < 16; ++k) {
        float4 a = fs[2 * k + h];
        float4 b = fd[2 * k + h];
        r[0] = r[0] + a.x * b.x;  r[1] = r[1] + a.y * b.y;
        r[2] = r[2] + a.z * b.z;  r[3] = r[3] + a.w * b.w;
    }
    float A = (r[0] + r[1]) + (r[2] + r[3]);
    return A + __shfl_xor(A, 1, 64);
}

// ---------------------------------------------------------------------------
// Fallback kernel (ws too small / odd feature count): round-1 proven path.
// ---------------------------------------------------------------------------
__global__ __launch_bounds__(256) void jaccard_edge_kernel(
    const int* __restrict__ ei, const float* __restrict__ w,
    const float* __restrict__ feat, float* __restrict__ out,
    int P, int E)
{
    int t    = blockIdx.x * blockDim.x + threadIdx.x;
    int pair = t >> 1;
    int half = t & 1;
    if (pair >= P) return;

    int src = ei[pair];
    int dst = ei[E + pair];

    float sim  = exact_sim_pairlanes(feat, src, dst, half);
    float keep = (sim >= THRESH) ? 1.0f : 0.0f;

    if (half == 0) {
        float diag = (src == dst) ? 2.0f : 1.0f;
        out[pair] = (w[pair] * keep) * diag;
        int m = P + pair;
        if (m < E) {
            int s2 = ei[m];
            int d2 = ei[E + m];
            if (s2 == dst && d2 == src) out[m] = (w[m] * keep) * diag;
            else                        out[m] = edge_out_scalar(feat, w[m], s2, d2);
        }
    }
}

// ---------------------------------------------------------------------------
// Pass A (round-4 v4, byte-identical): NO LDS, NO barriers. One quad per
// node. Lane q holds elements {8k+2q,8k+2q+1} (float2 idx 4k+q); sequential
// k == numpy order; shfl_xor(1),(2) == numpy pairwise tree -> bit-exact.
// Bad rows (na<0.03 / non-finite) NaN-poisoned.
// ---------------------------------------------------------------------------
__global__ __launch_bounds__(256) void norm_convert_kernel(
    const float* __restrict__ feat, __half* __restrict__ hfeat,
    float* __restrict__ nrm, int nNodes)
{
#pragma clang fp contract(off)
    int tid  = blockIdx.x * blockDim.x + threadIdx.x;
    int lane = tid & 63;
    int n    = (tid >> 6) * 16 + (lane >> 2);   // wave covers 16 nodes
    int q    = lane & 3;
    if (n >= nNodes) return;    // quad-uniform exit (n shared by all 4 lanes)

    const float2* row = (const float2*)(feat + (size_t)n * D_FEAT);
    float2 v[16];
#pragma unroll
    for (int k = 0; k < 16; ++k) v[k] = row[4 * k + q];

    float r0 = v[0].x * v[0].x;
    float r1 = v[0].y * v[0].y;
#pragma unroll
    for (int k = 1; k < 16; ++k) {
        r0 = r0 + v[k].x * v[k].x;
        r1 = r1 + v[k].y * v[k].y;
    }
    float s  = r0 + r1;                     // r[2q] + r[2q+1]
    float ss = s + __shfl_xor(s, 1, 64);    // (s0+s1) | (s2+s3)
    ss       = ss + __shfl_xor(ss, 2, 64);  // full numpy tree (quad-local)
    float na = __fsqrt_rn(ss);

    bool ok  = isfinite(na) && (na >= 0.03f);
    float r  = ok ? (1.0f / na) : __builtin_nanf("");

    if (q == 0) nrm[n] = na;                // exact numpy node_norm

    __half* orow = hfeat + (size_t)n * D_FEAT;
#pragma unroll
    for (int k = 0; k < 16; ++k) {
        __half2 h = __floats2half2_rn(v[k].x * r, v[k].y * r);
        *(__half2*)(orow + 8 * k + 2 * q) = h;
    }
}

// ---------------------------------------------------------------------------
// fdot2 helper
// ---------------------------------------------------------------------------
__device__ __forceinline__ float dot8_f16(uint4 ua, uint4 ub, float acc) {
    acc = __builtin_amdgcn_fdot2(__builtin_bit_cast(half2_t, ua.x),
                                 __builtin_bit_cast(half2_t, ub.x), acc, false);
    acc = __builtin_amdgcn_fdot2(__builtin_bit_cast(half2_t, ua.y),
                                 __builtin_bit_cast(half2_t, ub.y), acc, false);
    acc = __builtin_amdgcn_fdot2(__builtin_bit_cast(half2_t, ua.z),
                                 __builtin_bit_cast(half2_t, ub.z), acc, false);
    acc = __builtin_amdgcn_fdot2(__builtin_bit_cast(half2_t, ua.w),
                                 __builtin_bit_cast(half2_t, ub.w), acc, false);
    return acc;
}

// ---------------------------------------------------------------------------
// Pass B (proven round-1 body, now RANGE-PARTITIONED [pairLo, pairHi) so each
// half runs ~28 µs -> pass A becomes visible in rocprof top-5. Outputs are a
// clean partition of [0,P); per-pair math byte-identical to the proven v1.
// ---------------------------------------------------------------------------
__global__ __launch_bounds__(256) void jaccard_edge_f16u_kernel(
    const int* __restrict__ ei, const float* __restrict__ w,
    const float* __restrict__ feat, const __half* __restrict__ hfeat,
    const float* __restrict__ nrm, float* __restrict__ out,
    int pairLo, int pairHi, int P, int E)
{
#pragma clang fp contract(off)
    int t    = blockIdx.x * blockDim.x + threadIdx.x;
    int pair = (t >> 2) + pairLo;
    int q    = t & 3;
    if (pair >= pairHi) return;

    int src = __builtin_nontemporal_load(ei + pair);
    int dst = __builtin_nontemporal_load(ei + E + pair);

    float wp  = __builtin_nontemporal_load(w + pair);
    int   m   = P + pair;
    bool  hasm = (m < E);
    int s2 = 0, d2 = 0;
    float wm = 0.f;
    if (hasm) {
        s2 = __builtin_nontemporal_load(ei + m);
        d2 = __builtin_nontemporal_load(ei + E + m);
        wm = __builtin_nontemporal_load(w + m);
    }

    const uint4* ha = (const uint4*)(hfeat + (size_t)src * D_FEAT);
    const uint4* hb = (const uint4*)(hfeat + (size_t)dst * D_FEAT);

    uint4 A[4], B[4];
#pragma unroll
    for (int k = 0; k < 4; ++k) {
        A[k] = ha[4 * k + q];
        B[k] = hb[4 * k + q];
    }

    float d = 0.f;
#pragma unroll
    for (int k = 0; k < 4; ++k) d = dot8_f16(A[k], B[k], d);

    // quad butterfly: bit-identical on all 4 lanes (IEEE a+b==b+a)
    d += __shfl_xor(d, 1, 64);
    float dot = d + __shfl_xor(d, 2, 64);

    float diff = dot - THRESH;
    const float bnd = 1.2e-3f;

    float keep;
    if (fabsf(diff) > bnd && fabsf(dot) < 2.0f) {   // quad-uniform decision
        keep = (diff >= 0.f) ? 1.0f : 0.0f;
    } else {
        // exact numpy sim: exact inner (fp32, numpy order) / exact denominator
        float se = 0.f;
        if (q < 2) {
            float inner = exact_inner_pairlanes(feat, src, dst, q);
            float den   = nrm[src] * nrm[dst] + EPS_F;   // mul then add
            se = inner / den;
        }
        keep = (se >= THRESH) ? 1.0f : 0.0f;   // valid on lane q==0 (writer)
    }

    if (q == 0) {
        float diag = (src == dst) ? 2.0f : 1.0f;
        __builtin_nontemporal_store((wp * keep) * diag, out + pair);
        if (hasm) {
            if (s2 == dst && d2 == src) {
                __builtin_nontemporal_store((wm * keep) * diag, out + m);
            } else {
                out[m] = edge_out_scalar(feat, wm, s2, d2);
            }
        }
    }
}

extern "C" void kernel_launch(void* const* d_in, const int* in_sizes, int n_in,
                              void* d_out, int out_size, void* d_ws, size_t ws_size,
                              hipStream_t stream) {
    const int*   ei   = (const int*)d_in[0];     // [2, E] flattened (int32)
    const float* w    = (const float*)d_in[1];   // [E]
    const float* feat = (const float*)d_in[2];   // [N, 128]
    float*       out  = (float*)d_out;           // [E]

    int E = in_sizes[1];
    int P = E - E / 2;                 // ceil(E/2)
    long nfeat = in_sizes[2];
    long nNodes = nfeat / D_FEAT;
    size_t need = (size_t)nfeat * sizeof(__half) + (size_t)nNodes * sizeof(float);

    if (P <= 0) return;

    if (ws_size < need || (nfeat % D_FEAT) != 0) {
        int threads = 2 * P;
        int grid = (threads + 255) / 256;
        jaccard_edge_kernel<<<grid, 256, 0, stream>>>(ei, w, feat, out, P, E);
        return;
    }

    __half* hfeat = (__half*)d_ws;
    float*  nrm   = (float*)((char*)d_ws + (size_t)nfeat * sizeof(__half));

    // Pass A: one quad per node -> 16 nodes per wave -> 64 nodes per block
    long nWaves = (nNodes + 15) / 16;
    long tA = nWaves * 64;
    int gridA = (int)((tA + 255) / 256);
    norm_convert_kernel<<<gridA, 256, 0, stream>>>(feat, hfeat, nrm, (int)nNodes);

    // Pass B: two half-range launches (diagnostic split; clean partition)
    int Ph = P / 2;
    if (Ph > 0) {
        int t1 = 4 * Ph;
        jaccard_edge_f16u_kernel<<<(t1 + 255) / 256, 256, 0, stream>>>(
            ei, w, feat, hfeat, nrm, out, 0, Ph, P, E);
    }
    if (P > Ph) {
        int t2 = 4 * (P - Ph);
        jaccard_edge_f16u_kernel<<<(t2 + 255) / 256, 256, 0, stream>>>(
            ei, w, feat, hfeat, nrm, out, Ph, P, P, E);
    }
}

// Round 10
// 153.486 us; speedup vs baseline: 1.9482x; 1.0245x over previous
//
#include <hip/hip_runtime.h>
#include <hip/hip_fp16.h>

#define D_FEAT 128
#define THRESH 0.01f
#define EPS_F  1e-8f

typedef _Float16 half2_t __attribute__((ext_vector_type(2)));

// ---------------------------------------------------------------------------
// Exact helpers: bit-exact replication of numpy's fp32 pipeline
// (8-accumulator pairwise sum). Proven absmax=0 in prior rounds.
// ---------------------------------------------------------------------------

__device__ float edge_out_scalar(const float* __restrict__ feat,
                                 float w, int s, int d) {
#pragma clang fp contract(off)
    const float* fs = feat + (size_t)s * D_FEAT;
    const float* fd = feat + (size_t)d * D_FEAT;
    float r[8], rs[8], rd[8];
#pragma unroll
    for (int j = 0; j < 8; ++j) {
        float a = fs[j], b = fd[j];
        r[j]  = a * b;
        rs[j] = a * a;
        rd[j] = b * b;
    }
    for (int k = 1; k < 16; ++k) {
#pragma unroll
        for (int j = 0; j < 8; ++j) {
            float a = fs[8 * k + j], b = fd[8 * k + j];
            r[j]  = r[j]  + a * b;
            rs[j] = rs[j] + a * a;
            rd[j] = rd[j] + b * b;
        }
    }
    float inner = ((r[0]  + r[1])  + (r[2]  + r[3]))  + ((r[4]  + r[5])  + (r[6]  + r[7]));
    float ss    = ((rs[0] + rs[1]) + (rs[2] + rs[3])) + ((rs[4] + rs[5]) + (rs[6] + rs[7]));
    float dd    = ((rd[0] + rd[1]) + (rd[2] + rd[3])) + ((rd[4] + rd[5]) + (rd[6] + rd[7]));
    float ns = __fsqrt_rn(ss);
    float nd = __fsqrt_rn(dd);
    float denom = ns * nd + EPS_F;
    float sim = inner / denom;
    float keep = (sim >= THRESH) ? 1.0f : 0.0f;
    float diag = (s == d) ? 2.0f : 1.0f;
    return (w * keep) * diag;
}

__device__ __forceinline__ float exact_sim_pairlanes(const float* __restrict__ feat,
                                                     int src, int dst, int h) {
#pragma clang fp contract(off)
    const float4* fs = (const float4*)(feat + (size_t)src * D_FEAT);
    const float4* fd = (const float4*)(feat + (size_t)dst * D_FEAT);
    float r[4], rs[4], rd[4];
    {
        float4 a = fs[h];
        float4 b = fd[h];
        r[0]  = a.x * b.x; r[1]  = a.y * b.y; r[2]  = a.z * b.z; r[3]  = a.w * b.w;
        rs[0] = a.x * a.x; rs[1] = a.y * a.y; rs[2] = a.z * a.z; rs[3] = a.w * a.w;
        rd[0] = b.x * b.x; rd[1] = b.y * b.y; rd[2] = b.z * b.z; rd[3] = b.w * b.w;
    }
#pragma unroll
    for (int k = 1; k < 16; ++k) {
        float4 a = fs[2 * k + h];
        float4 b = fd[2 * k + h];
        r[0]  = r[0]  + a.x * b.x;  r[1]  = r[1]  + a.y * b.y;
        r[2]  = r[2]  + a.z * b.z;  r[3]  = r[3]  + a.w * b.w;
        rs[0] = rs[0] + a.x * a.x;  rs[1] = rs[1] + a.y * a.y;
        rs[2] = rs[2] + a.z * a.z;  rs[3] = rs[3] + a.w * a.w;
        rd[0] = rd[0] + b.x * b.x;  rd[1] = rd[1] + b.y * b.y;
        rd[2] = rd[2] + b.z * b.z;  rd[3] = rd[3] + b.w * b.w;
    }
    float A  = (r[0]  + r[1])  + (r[2]  + r[3]);
    float As = (rs[0] + rs[1]) + (rs[2] + rs[3]);
    float Ad = (rd[0] + rd[1]) + (rd[2] + rd[3]);

    float inner = A  + __shfl_xor(A, 1, 64);
    float ssE   = As + __shfl_xor(As, 1, 64);
    float ddE   = Ad + __shfl_xor(Ad, 1, 64);

    float ns    = __fsqrt_rn(ssE);
    float nd    = __fsqrt_rn(ddE);
    float den   = ns * nd + EPS_F;
    return inner / den;
}

__device__ __forceinline__ float exact_inner_pairlanes(const float* __restrict__ feat,
                                                       int src, int dst, int h) {
#pragma clang fp contract(off)
    const float4* fs = (const float4*)(feat + (size_t)src * D_FEAT);
    const float4* fd = (const float4*)(feat + (size_t)dst * D_FEAT);
    float r[4];
    {
        float4 a = fs[h];
        float4 b = fd[h];
        r[0] = a.x * b.x; r[1] = a.y * b.y; r[2] = a.z * b.z; r[3] = a.w * b.w;
    }
#pragma unroll
    for (int k = 1; k < 16; ++k) {
        float4 a = fs[2 * k + h];
        float4 b = fd[2 * k + h];
        r[0] = r[0] + a.x * b.x;  r[1] = r[1] + a.y * b.y;
        r[2] = r[2] + a.z * b.z;  r[3] = r[3] + a.w * b.w;
    }
    float A = (r[0] + r[1]) + (r[2] + r[3]);
    return A + __shfl_xor(A, 1, 64);
}

// ---------------------------------------------------------------------------
// Fallback kernel (ws too small / odd feature count): round-1 proven path.
// ---------------------------------------------------------------------------
__global__ __launch_bounds__(256) void jaccard_edge_kernel(
    const int* __restrict__ ei, const float* __restrict__ w,
    const float* __restrict__ feat, float* __restrict__ out,
    int P, int E)
{
    int t    = blockIdx.x * blockDim.x + threadIdx.x;
    int pair = t >> 1;
    int half = t & 1;
    if (pair >= P) return;

    int src = ei[pair];
    int dst = ei[E + pair];

    float sim  = exact_sim_pairlanes(feat, src, dst, half);
    float keep = (sim >= THRESH) ? 1.0f : 0.0f;

    if (half == 0) {
        float diag = (src == dst) ? 2.0f : 1.0f;
        out[pair] = (w[pair] * keep) * diag;
        int m = P + pair;
        if (m < E) {
            int s2 = ei[m];
            int d2 = ei[E + m];
            if (s2 == dst && d2 == src) out[m] = (w[m] * keep) * diag;
            else                        out[m] = edge_out_scalar(feat, w[m], s2, d2);
        }
    }
}

// ---------------------------------------------------------------------------
// Pass A (round-4 v4, byte-identical): NO LDS, NO barriers. One quad per
// node. Lane q holds elements {8k+2q,8k+2q+1} (float2 idx 4k+q); sequential
// k == numpy order; shfl_xor(1),(2) == numpy pairwise tree -> bit-exact.
// Bad rows (na<0.03 / non-finite) NaN-poisoned. Measured model: ~12 µs
// (77 MB at the 6.3 TB/s streaming ceiling) — below rocprof top-5 cutoff.
// ---------------------------------------------------------------------------
__global__ __launch_bounds__(256) void norm_convert_kernel(
    const float* __restrict__ feat, __half* __restrict__ hfeat,
    float* __restrict__ nrm, int nNodes)
{
#pragma clang fp contract(off)
    int tid  = blockIdx.x * blockDim.x + threadIdx.x;
    int lane = tid & 63;
    int n    = (tid >> 6) * 16 + (lane >> 2);   // wave covers 16 nodes
    int q    = lane & 3;
    if (n >= nNodes) return;    // quad-uniform exit (n shared by all 4 lanes)

    const float2* row = (const float2*)(feat + (size_t)n * D_FEAT);
    float2 v[16];
#pragma unroll
    for (int k = 0; k < 16; ++k) v[k] = row[4 * k + q];

    float r0 = v[0].x * v[0].x;
    float r1 = v[0].y * v[0].y;
#pragma unroll
    for (int k = 1; k < 16; ++k) {
        r0 = r0 + v[k].x * v[k].x;
        r1 = r1 + v[k].y * v[k].y;
    }
    float s  = r0 + r1;                     // r[2q] + r[2q+1]
    float ss = s + __shfl_xor(s, 1, 64);    // (s0+s1) | (s2+s3)
    ss       = ss + __shfl_xor(ss, 2, 64);  // full numpy tree (quad-local)
    float na = __fsqrt_rn(ss);

    bool ok  = isfinite(na) && (na >= 0.03f);
    float r  = ok ? (1.0f / na) : __builtin_nanf("");

    if (q == 0) nrm[n] = na;                // exact numpy node_norm

    __half* orow = hfeat + (size_t)n * D_FEAT;
#pragma unroll
    for (int k = 0; k < 16; ++k) {
        __half2 h = __floats2half2_rn(v[k].x * r, v[k].y * r);
        *(__half2*)(orow + 8 * k + 2 * q) = h;
    }
}

// ---------------------------------------------------------------------------
// fdot2 helper
// ---------------------------------------------------------------------------
__device__ __forceinline__ float dot8_f16(uint4 ua, uint4 ub, float acc) {
    acc = __builtin_amdgcn_fdot2(__builtin_bit_cast(half2_t, ua.x),
                                 __builtin_bit_cast(half2_t, ub.x), acc, false);
    acc = __builtin_amdgcn_fdot2(__builtin_bit_cast(half2_t, ua.y),
                                 __builtin_bit_cast(half2_t, ub.y), acc, false);
    acc = __builtin_amdgcn_fdot2(__builtin_bit_cast(half2_t, ua.z),
                                 __builtin_bit_cast(half2_t, ub.z), acc, false);
    acc = __builtin_amdgcn_fdot2(__builtin_bit_cast(half2_t, ua.w),
                                 __builtin_bit_cast(half2_t, ub.w), acc, false);
    return acc;
}

// ---------------------------------------------------------------------------
// Pass B (proven 56 µs): quad layout, 4 lanes/pair. Screen = fdot2 vs
// CONSTANT rigorous bound 1.2e-3; |dot|>=2 or NaN -> exact; borderline
// (~1.2%) -> exact fp32 numpy sim. Saturation established: MLP-doubling
// null (R2), locality binning counterproductive (R3); miss path steady at
// 3.4-3.5 TB/s, delivered gather ~7.3 TB/s.
// ---------------------------------------------------------------------------
__global__ __launch_bounds__(256) void jaccard_edge_f16u_kernel(
    const int* __restrict__ ei, const float* __restrict__ w,
    const float* __restrict__ feat, const __half* __restrict__ hfeat,
    const float* __restrict__ nrm, float* __restrict__ out, int P, int E)
{
#pragma clang fp contract(off)
    int t    = blockIdx.x * blockDim.x + threadIdx.x;
    int pair = t >> 2;
    int q    = t & 3;
    if (pair >= P) return;

    int src = __builtin_nontemporal_load(ei + pair);
    int dst = __builtin_nontemporal_load(ei + E + pair);

    float wp  = __builtin_nontemporal_load(w + pair);
    int   m   = P + pair;
    bool  hasm = (m < E);
    int s2 = 0, d2 = 0;
    float wm = 0.f;
    if (hasm) {
        s2 = __builtin_nontemporal_load(ei + m);
        d2 = __builtin_nontemporal_load(ei + E + m);
        wm = __builtin_nontemporal_load(w + m);
    }

    const uint4* ha = (const uint4*)(hfeat + (size_t)src * D_FEAT);
    const uint4* hb = (const uint4*)(hfeat + (size_t)dst * D_FEAT);

    uint4 A[4], B[4];
#pragma unroll
    for (int k = 0; k < 4; ++k) {
        A[k] = ha[4 * k + q];
        B[k] = hb[4 * k + q];
    }

    float d = 0.f;
#pragma unroll
    for (int k = 0; k < 4; ++k) d = dot8_f16(A[k], B[k], d);

    // quad butterfly: bit-identical on all 4 lanes (IEEE a+b==b+a)
    d += __shfl_xor(d, 1, 64);
    float dot = d + __shfl_xor(d, 2, 64);

    float diff = dot - THRESH;
    const float bnd = 1.2e-3f;

    float keep;
    if (fabsf(diff) > bnd && fabsf(dot) < 2.0f) {   // quad-uniform decision
        keep = (diff >= 0.f) ? 1.0f : 0.0f;
    } else {
        // exact numpy sim: exact inner (fp32, numpy order) / exact denominator
        float se = 0.f;
        if (q < 2) {
            float inner = exact_inner_pairlanes(feat, src, dst, q);
            float den   = nrm[src] * nrm[dst] + EPS_F;   // mul then add
            se = inner / den;
        }
        keep = (se >= THRESH) ? 1.0f : 0.0f;   // valid on lane q==0 (writer)
    }

    if (q == 0) {
        float diag = (src == dst) ? 2.0f : 1.0f;
        __builtin_nontemporal_store((wp * keep) * diag, out + pair);
        if (hasm) {
            if (s2 == dst && d2 == src) {
                __builtin_nontemporal_store((wm * keep) * diag, out + m);
            } else {
                out[m] = edge_out_scalar(feat, wm, s2, d2);
            }
        }
    }
}

extern "C" void kernel_launch(void* const* d_in, const int* in_sizes, int n_in,
                              void* d_out, int out_size, void* d_ws, size_t ws_size,
                              hipStream_t stream) {
    const int*   ei   = (const int*)d_in[0];     // [2, E] flattened (int32)
    const float* w    = (const float*)d_in[1];   // [E]
    const float* feat = (const float*)d_in[2];   // [N, 128]
    float*       out  = (float*)d_out;           // [E]

    int E = in_sizes[1];
    int P = E - E / 2;                 // ceil(E/2)
    long nfeat = in_sizes[2];
    long nNodes = nfeat / D_FEAT;
    size_t need = (size_t)nfeat * sizeof(__half) + (size_t)nNodes * sizeof(float);

    if (P <= 0) return;

    if (ws_size < need || (nfeat % D_FEAT) != 0) {
        int threads = 2 * P;
        int grid = (threads + 255) / 256;
        jaccard_edge_kernel<<<grid, 256, 0, stream>>>(ei, w, feat, out, P, E);
        return;
    }

    __half* hfeat = (__half*)d_ws;
    float*  nrm   = (float*)((char*)d_ws + (size_t)nfeat * sizeof(__half));

    // Pass A: one quad per node -> 16 nodes per wave -> 64 nodes per block
    long nWaves = (nNodes + 15) / 16;
    long tA = nWaves * 64;
    int gridA = (int)((tA + 255) / 256);
    norm_convert_kernel<<<gridA, 256, 0, stream>>>(feat, hfeat, nrm, (int)nNodes);

    // Pass B: single full-range launch (the 2-launch config is the best
    // measured family: 152.8-154.4 µs; the R9 diagnostic 3-launch split cost
    // ~3 µs and has served its purpose)
    int tB = 4 * P;
    jaccard_edge_f16u_kernel<<<(tB + 255) / 256, 256, 0, stream>>>(
        ei, w, feat, hfeat, nrm, out, P, E);
}